// Round 2
// baseline (334.359 us; speedup 1.0000x reference)
//
#include <hip/hip_runtime.h>
#include <math.h>

#define BN 8
#define C1 256
#define C2 128
#define WD 512

typedef float  f32x4  __attribute__((ext_vector_type(4)));
typedef short  bf16x8 __attribute__((ext_vector_type(8)));
typedef unsigned short ushort_t;
typedef ushort_t us8 __attribute__((ext_vector_type(8)));
typedef ushort_t us4 __attribute__((ext_vector_type(4)));
typedef unsigned int u32;

__device__ __forceinline__ int clampi(int v, int lo, int hi) {
    return v < lo ? lo : (v > hi ? hi : v);
}
__device__ __forceinline__ float bf2f(ushort_t u) {
    return __uint_as_float(((unsigned int)u) << 16);
}
__device__ __forceinline__ ushort_t f2bf(float f) {
    unsigned int u = __float_as_uint(f);
    u = (u + 0x7fff + ((u >> 16) & 1)) >> 16;   // RNE
    return (ushort_t)u;
}
// global -> LDS direct DMA, 16B per lane; LDS dest is wave-uniform base + lane*16
__device__ __forceinline__ void gll16(const ushort_t* g, ushort_t* l) {
    __builtin_amdgcn_global_load_lds(
        (const __attribute__((address_space(1))) u32*)g,
        (__attribute__((address_space(3))) u32*)l, 16, 0, 0);
}

// ---------------- affine (wave-per-output): s1, s2, n1, n2 ----------------
__global__ __launch_bounds__(256)
void affine_kernel(const float* __restrict__ w, const float* __restrict__ n,
                   const float* __restrict__ A1w, const float* __restrict__ A1b,
                   const float* __restrict__ B1w, const float* __restrict__ B1b,
                   const float* __restrict__ A2w, const float* __restrict__ A2b,
                   const float* __restrict__ B2w, const float* __restrict__ B2b,
                   float* __restrict__ s1, float* __restrict__ s2,
                   float* __restrict__ n1, float* __restrict__ n2) {
    int tid = threadIdx.x;
    int gw = blockIdx.x * 4 + (tid >> 6);
    int lane = tid & 63;
    if (gw >= BN * 896) return;
    int b = gw / 896;
    int j = gw % 896;
    const float* vec; const float* M; const float* bias; float* out; int o;
    if (j < 256)      { o = j;       vec = w + b * WD; M = A1w; bias = A1b; out = s1 + b * 256; }
    else if (j < 512) { o = j - 256; vec = w + b * WD; M = A2w; bias = A2b; out = s2 + b * 256; }
    else if (j < 768) { o = j - 512; vec = n + b * WD; M = B1w; bias = B1b; out = n1 + b * 256; }
    else              { o = j - 768; vec = n + b * WD; M = B2w; bias = B2b; out = n2 + b * 128; }
    const float* row = M + (size_t)o * WD;
    int k0 = lane * 8;
    float4 v0 = *(const float4*)(vec + k0), v1 = *(const float4*)(vec + k0 + 4);
    float4 r0 = *(const float4*)(row + k0), r1 = *(const float4*)(row + k0 + 4);
    float acc = v0.x*r0.x + v0.y*r0.y + v0.z*r0.z + v0.w*r0.w
              + v1.x*r1.x + v1.y*r1.y + v1.z*r1.z + v1.w*r1.w;
    #pragma unroll
    for (int m = 1; m < 64; m <<= 1) acc += __shfl_xor(acc, m, 64);
    if (lane == 0) out[o] = acc + bias[o];
}

// ---------------- demod (wave-per-output) ----------------
__global__ __launch_bounds__(256)
void demod_kernel(const float* __restrict__ cw1, const float* __restrict__ cw2,
                  const float* __restrict__ s1, const float* __restrict__ s2,
                  float* __restrict__ d1, float* __restrict__ d2) {
    int tid = threadIdx.x;
    int gw = blockIdx.x * 4 + (tid >> 6);
    int lane = tid & 63;
    if (gw >= BN * 384) return;
    int b = gw / 384;
    int j = gw % 384;
    const float* wbase; const float* s; float* dout; int o;
    if (j < 256) { o = j;       wbase = cw1; s = s1 + b * 256; dout = d1 + b * 256; }
    else         { o = j - 256; wbase = cw2; s = s2 + b * 256; dout = d2 + b * 128; }
    float acc = 0.f;
    #pragma unroll
    for (int i = 0; i < 4; i++) {
        int ic = lane * 4 + i;
        float sv = s[ic]; sv *= sv;
        const float* wk = wbase + ((size_t)o * 256 + ic) * 9;
        float t = 0.f;
        #pragma unroll
        for (int k = 0; k < 9; k++) t += wk[k] * wk[k];
        acc += t * sv;
    }
    #pragma unroll
    for (int m = 1; m < 64; m <<= 1) acc += __shfl_xor(acc, m, 64);
    if (lane == 0) dout[o] = rsqrtf(acc + 1e-5f);
}

// ---- weight prep -> bf16, layout wT[tap][oc][256 ic] (direct A-frag global loads) ----
__global__ __launch_bounds__(256)
void wprep_kernel(const float* __restrict__ cw1, const float* __restrict__ cw2,
                  ushort_t* __restrict__ wT1, ushort_t* __restrict__ wT2) {
    int idx = blockIdx.x * 256 + threadIdx.x;
    if (idx < 9 * 256 * 256) {
        int tap = idx >> 16;
        int oc = (idx >> 8) & 255;
        int ic = idx & 255;
        wT1[idx] = f2bf(cw1[((size_t)(oc * 256 + ic)) * 9 + tap]);
    } else if (idx < 9 * 256 * 256 + 9 * 128 * 256) {
        int e = idx - 9 * 256 * 256;
        int tap = e >> 15;
        int oc = (e >> 8) & 127;
        int ic = e & 255;
        wT2[e] = f2bf(cw2[((size_t)(oc * 256 + ic)) * 9 + tap]);
    }
}

// -------- xprep: x[b][ic][y][x] f32 -> xTp[b][64*64][256] bf16 (UNPADDED), styles folded --------
__global__ __launch_bounds__(512)
void xprep_kernel(const float* __restrict__ x, const float* __restrict__ s1,
                  ushort_t* __restrict__ xTp) {
    int tid = threadIdx.x;
    int b = blockIdx.y;
    int px_lin = blockIdx.x * 16 + (tid >> 5);
    int ic8 = tid & 31;
    const float* xb = x + (((size_t)b * C1) << 12) + px_lin;
    float4 slo = *(const float4*)(s1 + b * 256 + ic8 * 8);
    float4 shi = *(const float4*)(s1 + b * 256 + ic8 * 8 + 4);
    float sv[8] = {slo.x, slo.y, slo.z, slo.w, shi.x, shi.y, shi.z, shi.w};
    us8 h;
    #pragma unroll
    for (int j = 0; j < 8; j++) {
        float v = xb[((size_t)(ic8 * 8 + j)) << 12];
        h[j] = f2bf(v * sv[j]);
    }
    *(us8*)(xTp + ((size_t)b << 20) + (size_t)px_lin * 256 + ic8 * 8) = h;
}

// -------- upsample: y1T[b][64*64][256] -> y1up[b][128*128][256] (UNPADDED), *s2 folded --------
__global__ __launch_bounds__(256)
void upsample_kernel(const ushort_t* __restrict__ y1T, const float* __restrict__ s2,
                     ushort_t* __restrict__ y1up) {
    int flat = blockIdx.x * 256 + threadIdx.x;
    int b = blockIdx.y;
    int ic8 = flat & 31;
    int pxl = flat >> 5;
    int ux = pxl & 127, uy = pxl >> 7;
    int jyA; float wyA;
    if (uy & 1) { jyA = uy >> 1;       wyA = 0.75f; }
    else        { jyA = (uy >> 1) - 1; wyA = 0.25f; }
    int jxA; float wxA;
    if (ux & 1) { jxA = ux >> 1;       wxA = 0.75f; }
    else        { jxA = (ux >> 1) - 1; wxA = 0.25f; }
    int yA = clampi(jyA, 0, 63), yB = clampi(jyA + 1, 0, 63);
    int xA = clampi(jxA, 0, 63), xB = clampi(jxA + 1, 0, 63);
    float wyB = 1.f - wyA, wxB = 1.f - wxA;
    const ushort_t* yb = y1T + (((size_t)b) << 20) + ic8 * 8;
    us8 qAA = *(const us8*)(yb + (size_t)(yA * 64 + xA) * 256);
    us8 qAB = *(const us8*)(yb + (size_t)(yA * 64 + xB) * 256);
    us8 qBA = *(const us8*)(yb + (size_t)(yB * 64 + xA) * 256);
    us8 qBB = *(const us8*)(yb + (size_t)(yB * 64 + xB) * 256);
    float4 slo = *(const float4*)(s2 + b * 256 + ic8 * 8);
    float4 shi = *(const float4*)(s2 + b * 256 + ic8 * 8 + 4);
    float sv[8] = {slo.x, slo.y, slo.z, slo.w, shi.x, shi.y, shi.z, shi.w};
    us8 h;
    #pragma unroll
    for (int j = 0; j < 8; j++) {
        float v = wyA * (wxA * bf2f(qAA[j]) + wxB * bf2f(qAB[j]))
                + wyB * (wxA * bf2f(qBA[j]) + wxB * bf2f(qBB[j]));
        h[j] = f2bf(v * sv[j]);
    }
    *(us8*)(y1up + ((size_t)b << 22) + (size_t)(uy * 128 + ux) * 256 + ic8 * 8) = h;
}

// =========== conv MFMA v2: single-barrier pipelined kc loop ===========
// Block: 64 oc x (16x16 px), 4 waves. Wave = 32 oc (mt=2) x 128 px (nt=8).
//   wave w: ochalf = w>>1 (oc +0/+32), pxhalf = w&1 (px rows +0/+8).
// Act: global_load_lds DMA -> double-buffered LDS (2 x 20736 B), q-major planes
//   (slot u = q*324 + py*18 + pxx), halo via zero-page redirect of OOB lanes.
// Weights: per-kc preload of 18 A-frags straight from L2 into VGPRs
//   (wT[tap][oc][256ic]; lane: oc=ocbase+(l&15), ic=kc*32+(l>>4)*8 — the exact
//   mfma_16x16x32 A mapping). Weights never touch LDS.
// One __syncthreads per kc (its implicit vmcnt(0) covers the DMA); staging of
// buf[kc^1] overlaps the whole kc compute. w-loads are issued BEFORE the DMA
// batch so compiler's counted vmcnt on wf never drains the staging loads.
template<int IW, int OCTOT, int TPR, bool IS_CONV2>
__global__ __launch_bounds__(256, 2)
void conv_mfma(const ushort_t* __restrict__ inp, const ushort_t* __restrict__ wT,
               const float* __restrict__ dmod, const float* __restrict__ nza,
               ushort_t* __restrict__ outT,
               const float* __restrict__ rgb_in, const float* __restrict__ rw,
               const float* __restrict__ rb, float* __restrict__ xout,
               float* __restrict__ rgbo, const ushort_t* __restrict__ zpage) {
    __shared__ __align__(16) ushort_t actS[2 * 10368];   // 41472 B

    const int b = blockIdx.z, ocg = blockIdx.y, tile = blockIdx.x;
    const int tyT = tile / TPR, txT = tile % TPR;
    const int ty0 = tyT * 16, tx0 = txT * 16;
    const int tid = threadIdx.x, lane = tid & 63, wave = tid >> 6;
    const int col = lane & 15, quad = lane >> 4;
    const int ochalf = wave >> 1, pxhalf = wave & 1;

    const ushort_t* inb = inp + (size_t)b * IW * IW * 256;

    // act DMA source pointers (kc-invariant; OOB -> zero page)
    const ushort_t* asrc[6];
    #pragma unroll
    for (int c = 0; c < 6; c++) {
        int u = tid + 256 * c;
        int q = u / 324, px = u - q * 324;
        int py = px / 18, pxx = px - py * 18;
        int gy = ty0 + py - 1, gx = tx0 + pxx - 1;
        bool ok = (u < 1296) && (gy >= 0) && (gy < IW) && (gx >= 0) && (gx < IW);
        asrc[c] = ok ? (inb + (size_t)(gy * IW + gx) * 256 + q * 8) : zpage;
    }
    // weight lane base: oc = ocg*64 + ochalf*32 + (l&15), ic-suboffset (l>>4)*8
    const ushort_t* wlane = wT + (size_t)(ocg * 64 + ochalf * 32 + col) * 256 + quad * 8;
    const int TAPSTR = OCTOT * 256;

#define STAGE(NXT, KC) { \
    ushort_t* dsb = actS + (NXT) * 10368 + (tid >> 6) * 512; \
    _Pragma("unroll") for (int c = 0; c < 5; c++) \
        gll16(asrc[c] + (KC) * 32, dsb + c * 2048); \
    if (tid < 16) gll16(asrc[5] + (KC) * 32, actS + (NXT) * 10368 + 5 * 2048); }

    f32x4 acc[2][8];
    #pragma unroll
    for (int mt = 0; mt < 2; mt++)
        #pragma unroll
        for (int nt = 0; nt < 8; nt++) acc[mt][nt] = (f32x4)(0.f);

    STAGE(0, 0);
    __syncthreads();   // implicit vmcnt(0): buf0 ready

    for (int kc = 0; kc < 8; kc++) {
        // 1) weight frags for this kc (global, L2-hot) — issued before the DMA
        bf16x8 wf[9][2];
        #pragma unroll
        for (int tap = 0; tap < 9; tap++) {
            wf[tap][0] = *(const bf16x8*)(wlane + tap * TAPSTR + kc * 32);
            wf[tap][1] = *(const bf16x8*)(wlane + tap * TAPSTR + 16 * 256 + kc * 32);
        }
        // 2) stage next kc's act tile into the other buffer (in flight all kc)
        if (kc < 7) STAGE((kc & 1) ^ 1, kc + 1);
        // 3) compute from current buffer
        const ushort_t* bbase = actS + (kc & 1) * 10368
                              + (quad * 324 + pxhalf * 144 + col) * 8;
        #pragma unroll
        for (int dx = 0; dx < 3; dx++) {
            bf16x8 bb[10];
            #pragma unroll
            for (int j = 0; j < 10; j++)
                bb[j] = *(const bf16x8*)(bbase + (j * 18 + dx) * 8);
            #pragma unroll
            for (int dy = 0; dy < 3; dy++) {
                #pragma unroll
                for (int mt = 0; mt < 2; mt++)
                    #pragma unroll
                    for (int nt = 0; nt < 8; nt++)
                        acc[mt][nt] = __builtin_amdgcn_mfma_f32_16x16x32_bf16(
                            wf[dy * 3 + dx][mt], bb[nt + dy], acc[mt][nt], 0, 0, 0);
            }
        }
        __syncthreads();   // readers done + next buffer's DMA drained
    }
#undef STAGE

    if constexpr (!IS_CONV2) {
        // stage output tile in LDS (free after final barrier), 128B-coalesced stores
        ushort_t* oS = actS;   // 256 px * 80 us = 40960 B <= 41472
        #pragma unroll
        for (int mt = 0; mt < 2; mt++) {
            int ocl = ochalf * 32 + mt * 16 + quad * 4;
            int oc0 = ocg * 64 + ocl;
            float4 dv = *(const float4*)(dmod + b * OCTOT + oc0);
            float4 nv = *(const float4*)(nza + b * OCTOT + oc0);
            float dva[4] = {dv.x, dv.y, dv.z, dv.w};
            float nva[4] = {nv.x, nv.y, nv.z, nv.w};
            #pragma unroll
            for (int nt = 0; nt < 8; nt++) {
                int px = (pxhalf * 8 + nt) * 16 + col;
                us4 h;
                #pragma unroll
                for (int r = 0; r < 4; r++) {
                    float t = acc[mt][nt][r] * dva[r] + nva[r];
                    t = (t >= 0.f) ? t : 0.1f * t;
                    h[r] = f2bf(t);
                }
                *(us4*)(oS + px * 80 + ocl) = h;
            }
        }
        __syncthreads();
        #pragma unroll
        for (int p = 0; p < 8; p++) {
            int idx = tid + 256 * p;
            int px = idx >> 3, oc8 = idx & 7;
            us8 v = *(const us8*)(oS + px * 80 + oc8 * 8);
            int gy = ty0 + (px >> 4), gx = tx0 + (px & 15);
            *(us8*)(outT + ((size_t)b * IW * IW + gy * IW + gx) * 256 + ocg * 64 + oc8 * 8) = v;
        }
    } else {
        float dva[2][4], nva[2][4], rwa[3][2][4];
        #pragma unroll
        for (int mt = 0; mt < 2; mt++) {
            int oc0 = ocg * 64 + ochalf * 32 + mt * 16 + quad * 4;
            float4 dv = *(const float4*)(dmod + b * 128 + oc0);
            float4 nv = *(const float4*)(nza + b * 128 + oc0);
            dva[mt][0] = dv.x; dva[mt][1] = dv.y; dva[mt][2] = dv.z; dva[mt][3] = dv.w;
            nva[mt][0] = nv.x; nva[mt][1] = nv.y; nva[mt][2] = nv.z; nva[mt][3] = nv.w;
            #pragma unroll
            for (int c = 0; c < 3; c++) {
                float4 rv = *(const float4*)(rw + c * 128 + oc0);
                rwa[c][mt][0] = rv.x; rwa[c][mt][1] = rv.y; rwa[c][mt][2] = rv.z; rwa[c][mt][3] = rv.w;
            }
        }
        #pragma unroll
        for (int nt = 0; nt < 8; nt++) {
            int uy = ty0 + pxhalf * 8 + nt, ux = tx0 + col;
            float pc0 = 0.f, pc1 = 0.f, pc2 = 0.f;
            #pragma unroll
            for (int mt = 0; mt < 2; mt++) {
                int oc0 = ocg * 64 + ochalf * 32 + mt * 16 + quad * 4;
                #pragma unroll
                for (int r = 0; r < 4; r++) {
                    float t = acc[mt][nt][r] * dva[mt][r] + nva[mt][r];
                    t = (t >= 0.f) ? t : 0.1f * t;
                    xout[(((size_t)b * 128 + oc0 + r) << 14) + (uy << 7) + ux] = t;
                    pc0 += rwa[0][mt][r] * t;
                    pc1 += rwa[1][mt][r] * t;
                    pc2 += rwa[2][mt][r] * t;
                }
            }
            // reduce partial RGB across the 4 quads (same pixel) -> 1 atomic per wave
            pc0 += __shfl_xor(pc0, 16, 64); pc0 += __shfl_xor(pc0, 32, 64);
            pc1 += __shfl_xor(pc1, 16, 64); pc1 += __shfl_xor(pc1, 32, 64);
            pc2 += __shfl_xor(pc2, 16, 64); pc2 += __shfl_xor(pc2, 32, 64);
            if (quad == 0) {
                if (ocg == 0 && ochalf == 0) {
                    // residual + bias exactly once per pixel
                    int jyA; float wyA;
                    if (uy & 1) { jyA = uy >> 1;       wyA = 0.75f; }
                    else        { jyA = (uy >> 1) - 1; wyA = 0.25f; }
                    int jxA; float wxA;
                    if (ux & 1) { jxA = ux >> 1;       wxA = 0.75f; }
                    else        { jxA = (ux >> 1) - 1; wxA = 0.25f; }
                    int yA = clampi(jyA, 0, 63), yB = clampi(jyA + 1, 0, 63);
                    int xA = clampi(jxA, 0, 63), xB = clampi(jxA + 1, 0, 63);
                    float wyB = 1.f - wyA, wxB = 1.f - wxA;
                    const float* rp3 = rgb_in + (((size_t)b * 3) << 12);
                    #pragma unroll
                    for (int c = 0; c < 3; c++) {
                        const float* rc = rp3 + ((size_t)c << 12);
                        float up = wyA * (wxA * rc[(yA << 6) + xA] + wxB * rc[(yA << 6) + xB])
                                 + wyB * (wxA * rc[(yB << 6) + xA] + wxB * rc[(yB << 6) + xB]);
                        if (c == 0) pc0 += rb[0] + up;
                        else if (c == 1) pc1 += rb[1] + up;
                        else pc2 += rb[2] + up;
                    }
                }
                const float S = 0.70710678118654752f;
                atomicAdd(rgbo + (((size_t)b * 3 + 0) << 14) + (uy << 7) + ux, pc0 * S);
                atomicAdd(rgbo + (((size_t)b * 3 + 1) << 14) + (uy << 7) + ux, pc1 * S);
                atomicAdd(rgbo + (((size_t)b * 3 + 2) << 14) + (uy << 7) + ux, pc2 * S);
            }
        }
    }
}

extern "C" void kernel_launch(void* const* d_in, const int* in_sizes, int n_in,
                              void* d_out, int out_size, void* d_ws, size_t ws_size,
                              hipStream_t stream) {
    (void)in_sizes; (void)n_in; (void)out_size; (void)ws_size;
    const float* x     = (const float*)d_in[0];
    const float* w     = (const float*)d_in[1];
    const float* n     = (const float*)d_in[2];
    const float* rgb   = (const float*)d_in[3];
    const float* cw1   = (const float*)d_in[4];
    const float* A1w   = (const float*)d_in[5];
    const float* A1b   = (const float*)d_in[6];
    const float* B1w   = (const float*)d_in[7];
    const float* B1b   = (const float*)d_in[8];
    const float* cw2   = (const float*)d_in[9];
    const float* A2w   = (const float*)d_in[10];
    const float* A2b   = (const float*)d_in[11];
    const float* B2w   = (const float*)d_in[12];
    const float* B2b   = (const float*)d_in[13];
    const float* rgbw  = (const float*)d_in[14];
    const float* rgbb  = (const float*)d_in[15];

    char* ws = (char*)d_ws;
    float* s1 = (float*)(ws);
    float* s2 = (float*)(ws + 8192);
    float* d1 = (float*)(ws + 16384);
    float* d2 = (float*)(ws + 24576);
    float* n1 = (float*)(ws + 28672);
    float* n2 = (float*)(ws + 36864);
    ushort_t* wT1  = (ushort_t*)(ws + 40960);          // 1179648 B  [tap][256oc][256ic]
    ushort_t* wT2  = (ushort_t*)(ws + 1220608);        // 589824 B   [tap][128oc][256ic]
    ushort_t* xTp  = (ushort_t*)(ws + 1810432);        // 16777216 B [b][64*64][256]
    ushort_t* y1up = (ushort_t*)(ws + 18587648);       // 67108864 B [b][128*128][256]
    ushort_t* y1T  = (ushort_t*)(ws + 85696512);       // 16777216 B [b][64*64][256]
    ushort_t* zpage = (ushort_t*)(ws + 102473728);     // 4096 B zero page (halo)

    float* xout = (float*)d_out;
    float* rgbo = xout + (size_t)BN * C2 * 128 * 128;

    hipMemsetAsync(zpage, 0, 4096, stream);
    hipMemsetAsync(rgbo, 0, (size_t)BN * 3 * 128 * 128 * 4, stream);

    affine_kernel<<<1792, 256, 0, stream>>>(w, n, A1w, A1b, B1w, B1b, A2w, A2b, B2w, B2b,
                                            s1, s2, n1, n2);
    demod_kernel<<<768, 256, 0, stream>>>(cw1, cw2, s1, s2, d1, d2);
    wprep_kernel<<<(9 * 256 * 256 + 9 * 128 * 256 + 255) / 256, 256, 0, stream>>>(cw1, cw2, wT1, wT2);
    xprep_kernel<<<dim3(256, BN), 512, 0, stream>>>(x, s1, xTp);
    conv_mfma<64, 256, 4, false><<<dim3(16, 4, BN), 256, 0, stream>>>(
        xTp, wT1, d1, n1, y1T, nullptr, nullptr, nullptr, nullptr, nullptr, zpage);
    upsample_kernel<<<dim3(2048, BN), 256, 0, stream>>>(y1T, s2, y1up);
    conv_mfma<128, 128, 8, true><<<dim3(64, 2, BN), 256, 0, stream>>>(
        y1up, wT2, d2, n2, nullptr, rgb, rgbw, rgbb, xout, rgbo, zpage);
}

// Round 3
// 306.235 us; speedup vs baseline: 1.0918x; 1.0918x over previous
//
#include <hip/hip_runtime.h>
#include <math.h>

#define BN 8
#define C1 256
#define C2 128
#define WD 512

typedef float  f32x4  __attribute__((ext_vector_type(4)));
typedef short  bf16x8 __attribute__((ext_vector_type(8)));
typedef unsigned short ushort_t;
typedef ushort_t us8 __attribute__((ext_vector_type(8)));
typedef ushort_t us4 __attribute__((ext_vector_type(4)));
typedef unsigned int u32;

__device__ __forceinline__ int clampi(int v, int lo, int hi) {
    return v < lo ? lo : (v > hi ? hi : v);
}
__device__ __forceinline__ float bf2f(ushort_t u) {
    return __uint_as_float(((unsigned int)u) << 16);
}
__device__ __forceinline__ ushort_t f2bf(float f) {
    unsigned int u = __float_as_uint(f);
    u = (u + 0x7fff + ((u >> 16) & 1)) >> 16;   // RNE
    return (ushort_t)u;
}
// global -> LDS direct DMA, 16B per lane; LDS dest is wave-uniform base + lane*16
__device__ __forceinline__ void gll16(const ushort_t* g, ushort_t* l) {
    __builtin_amdgcn_global_load_lds(
        (const __attribute__((address_space(1))) u32*)g,
        (__attribute__((address_space(3))) u32*)l, 16, 0, 0);
}

// ---------------- affine (wave-per-output): s1, s2, n1, n2 ----------------
__global__ __launch_bounds__(256)
void affine_kernel(const float* __restrict__ w, const float* __restrict__ n,
                   const float* __restrict__ A1w, const float* __restrict__ A1b,
                   const float* __restrict__ B1w, const float* __restrict__ B1b,
                   const float* __restrict__ A2w, const float* __restrict__ A2b,
                   const float* __restrict__ B2w, const float* __restrict__ B2b,
                   float* __restrict__ s1, float* __restrict__ s2,
                   float* __restrict__ n1, float* __restrict__ n2) {
    int tid = threadIdx.x;
    int gw = blockIdx.x * 4 + (tid >> 6);
    int lane = tid & 63;
    if (gw >= BN * 896) return;
    int b = gw / 896;
    int j = gw % 896;
    const float* vec; const float* M; const float* bias; float* out; int o;
    if (j < 256)      { o = j;       vec = w + b * WD; M = A1w; bias = A1b; out = s1 + b * 256; }
    else if (j < 512) { o = j - 256; vec = w + b * WD; M = A2w; bias = A2b; out = s2 + b * 256; }
    else if (j < 768) { o = j - 512; vec = n + b * WD; M = B1w; bias = B1b; out = n1 + b * 256; }
    else              { o = j - 768; vec = n + b * WD; M = B2w; bias = B2b; out = n2 + b * 128; }
    const float* row = M + (size_t)o * WD;
    int k0 = lane * 8;
    float4 v0 = *(const float4*)(vec + k0), v1 = *(const float4*)(vec + k0 + 4);
    float4 r0 = *(const float4*)(row + k0), r1 = *(const float4*)(row + k0 + 4);
    float acc = v0.x*r0.x + v0.y*r0.y + v0.z*r0.z + v0.w*r0.w
              + v1.x*r1.x + v1.y*r1.y + v1.z*r1.z + v1.w*r1.w;
    #pragma unroll
    for (int m = 1; m < 64; m <<= 1) acc += __shfl_xor(acc, m, 64);
    if (lane == 0) out[o] = acc + bias[o];
}

// ---------------- demod (wave-per-output) ----------------
__global__ __launch_bounds__(256)
void demod_kernel(const float* __restrict__ cw1, const float* __restrict__ cw2,
                  const float* __restrict__ s1, const float* __restrict__ s2,
                  float* __restrict__ d1, float* __restrict__ d2) {
    int tid = threadIdx.x;
    int gw = blockIdx.x * 4 + (tid >> 6);
    int lane = tid & 63;
    if (gw >= BN * 384) return;
    int b = gw / 384;
    int j = gw % 384;
    const float* wbase; const float* s; float* dout; int o;
    if (j < 256) { o = j;       wbase = cw1; s = s1 + b * 256; dout = d1 + b * 256; }
    else         { o = j - 256; wbase = cw2; s = s2 + b * 256; dout = d2 + b * 128; }
    float acc = 0.f;
    #pragma unroll
    for (int i = 0; i < 4; i++) {
        int ic = lane * 4 + i;
        float sv = s[ic]; sv *= sv;
        const float* wk = wbase + ((size_t)o * 256 + ic) * 9;
        float t = 0.f;
        #pragma unroll
        for (int k = 0; k < 9; k++) t += wk[k] * wk[k];
        acc += t * sv;
    }
    #pragma unroll
    for (int m = 1; m < 64; m <<= 1) acc += __shfl_xor(acc, m, 64);
    if (lane == 0) dout[o] = rsqrtf(acc + 1e-5f);
}

// ---- weight prep -> bf16, layout wT[tap][oc][256 ic] (direct A-frag global loads) ----
__global__ __launch_bounds__(256)
void wprep_kernel(const float* __restrict__ cw1, const float* __restrict__ cw2,
                  ushort_t* __restrict__ wT1, ushort_t* __restrict__ wT2) {
    int idx = blockIdx.x * 256 + threadIdx.x;
    if (idx < 9 * 256 * 256) {
        int tap = idx >> 16;
        int oc = (idx >> 8) & 255;
        int ic = idx & 255;
        wT1[idx] = f2bf(cw1[((size_t)(oc * 256 + ic)) * 9 + tap]);
    } else if (idx < 9 * 256 * 256 + 9 * 128 * 256) {
        int e = idx - 9 * 256 * 256;
        int tap = e >> 15;
        int oc = (e >> 8) & 127;
        int ic = e & 255;
        wT2[e] = f2bf(cw2[((size_t)(oc * 256 + ic)) * 9 + tap]);
    }
}

// -------- xprep: x[b][ic][y][x] f32 -> xTp[b][64*64][256] bf16 (UNPADDED), styles folded --------
__global__ __launch_bounds__(512)
void xprep_kernel(const float* __restrict__ x, const float* __restrict__ s1,
                  ushort_t* __restrict__ xTp) {
    int tid = threadIdx.x;
    int b = blockIdx.y;
    int px_lin = blockIdx.x * 16 + (tid >> 5);
    int ic8 = tid & 31;
    const float* xb = x + (((size_t)b * C1) << 12) + px_lin;
    float4 slo = *(const float4*)(s1 + b * 256 + ic8 * 8);
    float4 shi = *(const float4*)(s1 + b * 256 + ic8 * 8 + 4);
    float sv[8] = {slo.x, slo.y, slo.z, slo.w, shi.x, shi.y, shi.z, shi.w};
    us8 h;
    #pragma unroll
    for (int j = 0; j < 8; j++) {
        float v = xb[((size_t)(ic8 * 8 + j)) << 12];
        h[j] = f2bf(v * sv[j]);
    }
    *(us8*)(xTp + ((size_t)b << 20) + (size_t)px_lin * 256 + ic8 * 8) = h;
}

// -------- upsample: y1T[b][64*64][256] -> y1up[b][128*128][256] (UNPADDED), *s2 folded --------
__global__ __launch_bounds__(256)
void upsample_kernel(const ushort_t* __restrict__ y1T, const float* __restrict__ s2,
                     ushort_t* __restrict__ y1up) {
    int flat = blockIdx.x * 256 + threadIdx.x;
    int b = blockIdx.y;
    int ic8 = flat & 31;
    int pxl = flat >> 5;
    int ux = pxl & 127, uy = pxl >> 7;
    int jyA; float wyA;
    if (uy & 1) { jyA = uy >> 1;       wyA = 0.75f; }
    else        { jyA = (uy >> 1) - 1; wyA = 0.25f; }
    int jxA; float wxA;
    if (ux & 1) { jxA = ux >> 1;       wxA = 0.75f; }
    else        { jxA = (ux >> 1) - 1; wxA = 0.25f; }
    int yA = clampi(jyA, 0, 63), yB = clampi(jyA + 1, 0, 63);
    int xA = clampi(jxA, 0, 63), xB = clampi(jxA + 1, 0, 63);
    float wyB = 1.f - wyA, wxB = 1.f - wxA;
    const ushort_t* yb = y1T + (((size_t)b) << 20) + ic8 * 8;
    us8 qAA = *(const us8*)(yb + (size_t)(yA * 64 + xA) * 256);
    us8 qAB = *(const us8*)(yb + (size_t)(yA * 64 + xB) * 256);
    us8 qBA = *(const us8*)(yb + (size_t)(yB * 64 + xA) * 256);
    us8 qBB = *(const us8*)(yb + (size_t)(yB * 64 + xB) * 256);
    float4 slo = *(const float4*)(s2 + b * 256 + ic8 * 8);
    float4 shi = *(const float4*)(s2 + b * 256 + ic8 * 8 + 4);
    float sv[8] = {slo.x, slo.y, slo.z, slo.w, shi.x, shi.y, shi.z, shi.w};
    us8 h;
    #pragma unroll
    for (int j = 0; j < 8; j++) {
        float v = wyA * (wxA * bf2f(qAA[j]) + wxB * bf2f(qAB[j]))
                + wyB * (wxA * bf2f(qBA[j]) + wxB * bf2f(qBB[j]));
        h[j] = f2bf(v * sv[j]);
    }
    *(us8*)(y1up + ((size_t)b << 22) + (size_t)(uy * 128 + ux) * 256 + ic8 * 8) = h;
}

// =========== conv MFMA v3: single barrier/kc, weights in regs prefetched kc-ahead ===========
// Block: 64 oc x (16x16 px), 4 waves. Wave = 16 oc x 256 px (nt=16), oc-slice = wave*16.
// Act: global_load_lds DMA -> double-buffered LDS (2 x 20736 B), q-major planes
//   (slot u = q*324 + py*18 + pxx), halo via zero-page redirect of OOB lanes.
// Weights: wf[9] A-frags in VGPRs; wfN[9] for kc+1 loaded from L2 at the TOP of kc
//   (full compute phase to cover latency — this was R2's bug), swapped after the barrier.
//   Weights never touch LDS -> no second barrier. LDS reads: B-frags only, 60/kc/wave.
// One __syncthreads per kc (implicit vmcnt(0) drains next buffer's DMA + wfN loads).
template<int IW, int OCTOT, int TPR, bool IS_CONV2>
__global__ __launch_bounds__(256, 2)
void conv_mfma(const ushort_t* __restrict__ inp, const ushort_t* __restrict__ wT,
               const float* __restrict__ dmod, const float* __restrict__ nza,
               ushort_t* __restrict__ outT,
               const float* __restrict__ rgb_in, const float* __restrict__ rw,
               const float* __restrict__ rb, float* __restrict__ xout,
               float* __restrict__ rgbo, const ushort_t* __restrict__ zpage) {
    __shared__ __align__(16) ushort_t actS[2 * 10368];   // 41472 B

    const int b = blockIdx.z, ocg = blockIdx.y, tile = blockIdx.x;
    const int tyT = tile / TPR, txT = tile % TPR;
    const int ty0 = tyT * 16, tx0 = txT * 16;
    const int tid = threadIdx.x, lane = tid & 63, wave = tid >> 6;
    const int col = lane & 15, quad = lane >> 4;

    const ushort_t* inb = inp + (size_t)b * IW * IW * 256;

    // act DMA source pointers (kc-invariant; OOB -> zero page)
    const ushort_t* asrc[6];
    #pragma unroll
    for (int c = 0; c < 6; c++) {
        int u = tid + 256 * c;
        int q = u / 324, px = u - q * 324;
        int py = px / 18, pxx = px - py * 18;
        int gy = ty0 + py - 1, gx = tx0 + pxx - 1;
        bool ok = (u < 1296) && (gy >= 0) && (gy < IW) && (gx >= 0) && (gx < IW);
        asrc[c] = ok ? (inb + (size_t)(gy * IW + gx) * 256 + q * 8) : zpage;
    }
    // weight lane addressing: oc = ocg*64 + wave*16 + col, ic = kc*32 + quad*8
    const ushort_t* wlane = wT + (size_t)(ocg * 64 + wave * 16 + col) * 256 + quad * 8;
    const int TAPSTR = OCTOT * 256;

#define STAGE(NXT, KC) { \
    ushort_t* dsb = actS + (NXT) * 10368 + (tid >> 6) * 512; \
    _Pragma("unroll") for (int c = 0; c < 5; c++) \
        gll16(asrc[c] + (KC) * 32, dsb + c * 2048); \
    if (tid < 16) gll16(asrc[5] + (KC) * 32, actS + (NXT) * 10368 + 5 * 2048); }

    f32x4 acc[16];
    #pragma unroll
    for (int nt = 0; nt < 16; nt++) acc[nt] = (f32x4)(0.f);

    bf16x8 wf[9], wfN[9];
    #pragma unroll
    for (int t = 0; t < 9; t++) wf[t] = *(const bf16x8*)(wlane + t * TAPSTR);
    STAGE(0, 0);
    __syncthreads();   // buf0 ready (implicit vmcnt(0))

    for (int kc = 0; kc < 8; kc++) {
        // prefetch NEXT kc: weights -> regs, act -> other LDS buffer (both in flight all kc)
        if (kc < 7) {
            #pragma unroll
            for (int t = 0; t < 9; t++)
                wfN[t] = *(const bf16x8*)(wlane + t * TAPSTR + (kc + 1) * 32);
            STAGE((kc & 1) ^ 1, kc + 1);
        }
        // compute from current buffer; B-frags only (weights already in regs)
        const ushort_t* bbase = actS + (kc & 1) * 10368 + (quad * 324 + col) * 8;
        #pragma unroll
        for (int h = 0; h < 2; h++) {
            #pragma unroll
            for (int dx = 0; dx < 3; dx++) {
                bf16x8 bb[10];
                #pragma unroll
                for (int j = 0; j < 10; j++)
                    bb[j] = *(const bf16x8*)(bbase + ((h * 8 + j) * 18 + dx) * 8);
                #pragma unroll
                for (int dy = 0; dy < 3; dy++)
                    #pragma unroll
                    for (int nt = 0; nt < 8; nt++)
                        acc[h * 8 + nt] = __builtin_amdgcn_mfma_f32_16x16x32_bf16(
                            wf[dy * 3 + dx], bb[nt + dy], acc[h * 8 + nt], 0, 0, 0);
            }
        }
        __syncthreads();   // readers done + next buffer's DMA + wfN drained
        if (kc < 7) {
            #pragma unroll
            for (int t = 0; t < 9; t++) wf[t] = wfN[t];
        }
    }
#undef STAGE

    if constexpr (!IS_CONV2) {
        // stage output tile in LDS (free after final barrier), 128B-coalesced stores
        ushort_t* oS = actS;   // 256 px * 80 us = 40960 B <= 41472
        const int ocl = wave * 16 + quad * 4;
        const int oc0 = ocg * 64 + ocl;
        float4 dv = *(const float4*)(dmod + b * OCTOT + oc0);
        float4 nv = *(const float4*)(nza + b * OCTOT + oc0);
        float dva[4] = {dv.x, dv.y, dv.z, dv.w};
        float nva[4] = {nv.x, nv.y, nv.z, nv.w};
        #pragma unroll
        for (int nt = 0; nt < 16; nt++) {
            int px = nt * 16 + col;
            us4 h;
            #pragma unroll
            for (int r = 0; r < 4; r++) {
                float t = acc[nt][r] * dva[r] + nva[r];
                t = (t >= 0.f) ? t : 0.1f * t;
                h[r] = f2bf(t);
            }
            *(us4*)(oS + px * 80 + ocl) = h;
        }
        __syncthreads();
        #pragma unroll
        for (int p = 0; p < 8; p++) {
            int idx = tid + 256 * p;
            int px = idx >> 3, oc8 = idx & 7;
            us8 v = *(const us8*)(oS + px * 80 + oc8 * 8);
            int gy = ty0 + (px >> 4), gx = tx0 + (px & 15);
            *(us8*)(outT + ((size_t)b * IW * IW + gy * IW + gx) * 256 + ocg * 64 + oc8 * 8) = v;
        }
    } else {
        const int oc0 = ocg * 64 + wave * 16 + quad * 4;
        float4 dv = *(const float4*)(dmod + b * 128 + oc0);
        float4 nv = *(const float4*)(nza + b * 128 + oc0);
        float dva[4] = {dv.x, dv.y, dv.z, dv.w};
        float nva[4] = {nv.x, nv.y, nv.z, nv.w};
        float rwa[3][4];
        #pragma unroll
        for (int c = 0; c < 3; c++) {
            float4 rv = *(const float4*)(rw + c * 128 + oc0);
            rwa[c][0] = rv.x; rwa[c][1] = rv.y; rwa[c][2] = rv.z; rwa[c][3] = rv.w;
        }
        #pragma unroll
        for (int nt = 0; nt < 16; nt++) {
            int uy = ty0 + nt, ux = tx0 + col;
            float pc0 = 0.f, pc1 = 0.f, pc2 = 0.f;
            #pragma unroll
            for (int r = 0; r < 4; r++) {
                float t = acc[nt][r] * dva[r] + nva[r];
                t = (t >= 0.f) ? t : 0.1f * t;
                xout[(((size_t)b * 128 + oc0 + r) << 14) + (uy << 7) + ux] = t;
                pc0 += rwa[0][r] * t;
                pc1 += rwa[1][r] * t;
                pc2 += rwa[2][r] * t;
            }
            // reduce partial RGB across the 4 quads (same pixel) -> 1 atomic per wave
            pc0 += __shfl_xor(pc0, 16, 64); pc0 += __shfl_xor(pc0, 32, 64);
            pc1 += __shfl_xor(pc1, 16, 64); pc1 += __shfl_xor(pc1, 32, 64);
            pc2 += __shfl_xor(pc2, 16, 64); pc2 += __shfl_xor(pc2, 32, 64);
            if (quad == 0) {
                if (ocg == 0 && wave == 0) {
                    // residual + bias exactly once per pixel
                    int jyA; float wyA;
                    if (uy & 1) { jyA = uy >> 1;       wyA = 0.75f; }
                    else        { jyA = (uy >> 1) - 1; wyA = 0.25f; }
                    int jxA; float wxA;
                    if (ux & 1) { jxA = ux >> 1;       wxA = 0.75f; }
                    else        { jxA = (ux >> 1) - 1; wxA = 0.25f; }
                    int yA = clampi(jyA, 0, 63), yB = clampi(jyA + 1, 0, 63);
                    int xA = clampi(jxA, 0, 63), xB = clampi(jxA + 1, 0, 63);
                    float wyB = 1.f - wyA, wxB = 1.f - wxA;
                    const float* rp3 = rgb_in + (((size_t)b * 3) << 12);
                    #pragma unroll
                    for (int c = 0; c < 3; c++) {
                        const float* rc = rp3 + ((size_t)c << 12);
                        float up = wyA * (wxA * rc[(yA << 6) + xA] + wxB * rc[(yA << 6) + xB])
                                 + wyB * (wxA * rc[(yB << 6) + xA] + wxB * rc[(yB << 6) + xB]);
                        if (c == 0) pc0 += rb[0] + up;
                        else if (c == 1) pc1 += rb[1] + up;
                        else pc2 += rb[2] + up;
                    }
                }
                const float S = 0.70710678118654752f;
                atomicAdd(rgbo + (((size_t)b * 3 + 0) << 14) + (uy << 7) + ux, pc0 * S);
                atomicAdd(rgbo + (((size_t)b * 3 + 1) << 14) + (uy << 7) + ux, pc1 * S);
                atomicAdd(rgbo + (((size_t)b * 3 + 2) << 14) + (uy << 7) + ux, pc2 * S);
            }
        }
    }
}

extern "C" void kernel_launch(void* const* d_in, const int* in_sizes, int n_in,
                              void* d_out, int out_size, void* d_ws, size_t ws_size,
                              hipStream_t stream) {
    (void)in_sizes; (void)n_in; (void)out_size; (void)ws_size;
    const float* x     = (const float*)d_in[0];
    const float* w     = (const float*)d_in[1];
    const float* n     = (const float*)d_in[2];
    const float* rgb   = (const float*)d_in[3];
    const float* cw1   = (const float*)d_in[4];
    const float* A1w   = (const float*)d_in[5];
    const float* A1b   = (const float*)d_in[6];
    const float* B1w   = (const float*)d_in[7];
    const float* B1b   = (const float*)d_in[8];
    const float* cw2   = (const float*)d_in[9];
    const float* A2w   = (const float*)d_in[10];
    const float* A2b   = (const float*)d_in[11];
    const float* B2w   = (const float*)d_in[12];
    const float* B2b   = (const float*)d_in[13];
    const float* rgbw  = (const float*)d_in[14];
    const float* rgbb  = (const float*)d_in[15];

    char* ws = (char*)d_ws;
    float* s1 = (float*)(ws);
    float* s2 = (float*)(ws + 8192);
    float* d1 = (float*)(ws + 16384);
    float* d2 = (float*)(ws + 24576);
    float* n1 = (float*)(ws + 28672);
    float* n2 = (float*)(ws + 36864);
    ushort_t* wT1  = (ushort_t*)(ws + 40960);          // 1179648 B  [tap][256oc][256ic]
    ushort_t* wT2  = (ushort_t*)(ws + 1220608);        // 589824 B   [tap][128oc][256ic]
    ushort_t* xTp  = (ushort_t*)(ws + 1810432);        // 16777216 B [b][64*64][256]
    ushort_t* y1up = (ushort_t*)(ws + 18587648);       // 67108864 B [b][128*128][256]
    ushort_t* y1T  = (ushort_t*)(ws + 85696512);       // 16777216 B [b][64*64][256]
    ushort_t* zpage = (ushort_t*)(ws + 102473728);     // 4096 B zero page (halo)

    float* xout = (float*)d_out;
    float* rgbo = xout + (size_t)BN * C2 * 128 * 128;

    hipMemsetAsync(zpage, 0, 4096, stream);
    hipMemsetAsync(rgbo, 0, (size_t)BN * 3 * 128 * 128 * 4, stream);

    affine_kernel<<<1792, 256, 0, stream>>>(w, n, A1w, A1b, B1w, B1b, A2w, A2b, B2w, B2b,
                                            s1, s2, n1, n2);
    demod_kernel<<<768, 256, 0, stream>>>(cw1, cw2, s1, s2, d1, d2);
    wprep_kernel<<<(9 * 256 * 256 + 9 * 128 * 256 + 255) / 256, 256, 0, stream>>>(cw1, cw2, wT1, wT2);
    xprep_kernel<<<dim3(256, BN), 512, 0, stream>>>(x, s1, xTp);
    conv_mfma<64, 256, 4, false><<<dim3(16, 4, BN), 256, 0, stream>>>(
        xTp, wT1, d1, n1, y1T, nullptr, nullptr, nullptr, nullptr, nullptr, zpage);
    upsample_kernel<<<dim3(2048, BN), 256, 0, stream>>>(y1T, s2, y1up);
    conv_mfma<128, 128, 8, true><<<dim3(64, 2, BN), 256, 0, stream>>>(
        y1up, wT2, d2, n2, nullptr, rgb, rgbw, rgbb, xout, rgbo, zpage);
}

// Round 4
// 283.634 us; speedup vs baseline: 1.1788x; 1.0797x over previous
//
#include <hip/hip_runtime.h>
#include <math.h>

#define BN 8
#define C1 256
#define C2 128
#define WD 512

typedef float  f32x4  __attribute__((ext_vector_type(4)));
typedef short  bf16x8 __attribute__((ext_vector_type(8)));
typedef unsigned short ushort_t;
typedef ushort_t us8 __attribute__((ext_vector_type(8)));
typedef ushort_t us4 __attribute__((ext_vector_type(4)));
typedef unsigned int u32;

__device__ __forceinline__ int clampi(int v, int lo, int hi) {
    return v < lo ? lo : (v > hi ? hi : v);
}
__device__ __forceinline__ float bf2f(ushort_t u) {
    return __uint_as_float(((unsigned int)u) << 16);
}
__device__ __forceinline__ ushort_t f2bf(float f) {
    unsigned int u = __float_as_uint(f);
    u = (u + 0x7fff + ((u >> 16) & 1)) >> 16;   // RNE
    return (ushort_t)u;
}

// ---------------- affine (wave-per-output): s1, s2, n1, n2 ----------------
__global__ __launch_bounds__(256)
void affine_kernel(const float* __restrict__ w, const float* __restrict__ n,
                   const float* __restrict__ A1w, const float* __restrict__ A1b,
                   const float* __restrict__ B1w, const float* __restrict__ B1b,
                   const float* __restrict__ A2w, const float* __restrict__ A2b,
                   const float* __restrict__ B2w, const float* __restrict__ B2b,
                   float* __restrict__ s1, float* __restrict__ s2,
                   float* __restrict__ n1, float* __restrict__ n2) {
    int tid = threadIdx.x;
    int gw = blockIdx.x * 4 + (tid >> 6);
    int lane = tid & 63;
    if (gw >= BN * 896) return;
    int b = gw / 896;
    int j = gw % 896;
    const float* vec; const float* M; const float* bias; float* out; int o;
    if (j < 256)      { o = j;       vec = w + b * WD; M = A1w; bias = A1b; out = s1 + b * 256; }
    else if (j < 512) { o = j - 256; vec = w + b * WD; M = A2w; bias = A2b; out = s2 + b * 256; }
    else if (j < 768) { o = j - 512; vec = n + b * WD; M = B1w; bias = B1b; out = n1 + b * 256; }
    else              { o = j - 768; vec = n + b * WD; M = B2w; bias = B2b; out = n2 + b * 128; }
    const float* row = M + (size_t)o * WD;
    int k0 = lane * 8;
    float4 v0 = *(const float4*)(vec + k0), v1 = *(const float4*)(vec + k0 + 4);
    float4 r0 = *(const float4*)(row + k0), r1 = *(const float4*)(row + k0 + 4);
    float acc = v0.x*r0.x + v0.y*r0.y + v0.z*r0.z + v0.w*r0.w
              + v1.x*r1.x + v1.y*r1.y + v1.z*r1.z + v1.w*r1.w;
    #pragma unroll
    for (int m = 1; m < 64; m <<= 1) acc += __shfl_xor(acc, m, 64);
    if (lane == 0) out[o] = acc + bias[o];
}

// ---------------- demod (wave-per-output) ----------------
__global__ __launch_bounds__(256)
void demod_kernel(const float* __restrict__ cw1, const float* __restrict__ cw2,
                  const float* __restrict__ s1, const float* __restrict__ s2,
                  float* __restrict__ d1, float* __restrict__ d2) {
    int tid = threadIdx.x;
    int gw = blockIdx.x * 4 + (tid >> 6);
    int lane = tid & 63;
    if (gw >= BN * 384) return;
    int b = gw / 384;
    int j = gw % 384;
    const float* wbase; const float* s; float* dout; int o;
    if (j < 256) { o = j;       wbase = cw1; s = s1 + b * 256; dout = d1 + b * 256; }
    else         { o = j - 256; wbase = cw2; s = s2 + b * 256; dout = d2 + b * 128; }
    float acc = 0.f;
    #pragma unroll
    for (int i = 0; i < 4; i++) {
        int ic = lane * 4 + i;
        float sv = s[ic]; sv *= sv;
        const float* wk = wbase + ((size_t)o * 256 + ic) * 9;
        float t = 0.f;
        #pragma unroll
        for (int k = 0; k < 9; k++) t += wk[k] * wk[k];
        acc += t * sv;
    }
    #pragma unroll
    for (int m = 1; m < 64; m <<= 1) acc += __shfl_xor(acc, m, 64);
    if (lane == 0) dout[o] = rsqrtf(acc + 1e-5f);
}

// ---- weight prep -> bf16.
//   wT1: chunked [kc][tap][256oc][32ic]  (for conv_mfma_ls / conv1)
//   wT2: flat    [tap][128oc][256ic]     (for conv_mfma_rp / conv2)
__global__ __launch_bounds__(256)
void wprep_kernel(const float* __restrict__ cw1, const float* __restrict__ cw2,
                  ushort_t* __restrict__ wT1, ushort_t* __restrict__ wT2) {
    int idx = blockIdx.x * 256 + threadIdx.x;
    if (idx < 8 * 9 * 256 * 32) {              // 589824 elements
        int icw = idx & 31;
        int r = idx >> 5;
        int oc = r & 255; r >>= 8;             // r < 72
        int tap = r % 9, kc = r / 9;
        int ic = kc * 32 + icw;
        wT1[idx] = f2bf(cw1[((size_t)(oc * 256 + ic)) * 9 + tap]);
    } else if (idx < 589824 + 9 * 128 * 256) { // + 294912 elements
        int e = idx - 589824;
        int tap = e >> 15;
        int oc = (e >> 8) & 127;
        int ic = e & 255;
        wT2[e] = f2bf(cw2[((size_t)(oc * 256 + ic)) * 9 + tap]);
    }
}

// -------- xprep: x[b][ic][y][x] f32 -> xTp[b][64*64][256] bf16 (UNPADDED), styles folded --------
__global__ __launch_bounds__(512)
void xprep_kernel(const float* __restrict__ x, const float* __restrict__ s1,
                  ushort_t* __restrict__ xTp) {
    int tid = threadIdx.x;
    int b = blockIdx.y;
    int px_lin = blockIdx.x * 16 + (tid >> 5);
    int ic8 = tid & 31;
    const float* xb = x + (((size_t)b * C1) << 12) + px_lin;
    float4 slo = *(const float4*)(s1 + b * 256 + ic8 * 8);
    float4 shi = *(const float4*)(s1 + b * 256 + ic8 * 8 + 4);
    float sv[8] = {slo.x, slo.y, slo.z, slo.w, shi.x, shi.y, shi.z, shi.w};
    us8 h;
    #pragma unroll
    for (int j = 0; j < 8; j++) {
        float v = xb[((size_t)(ic8 * 8 + j)) << 12];
        h[j] = f2bf(v * sv[j]);
    }
    *(us8*)(xTp + ((size_t)b << 20) + (size_t)px_lin * 256 + ic8 * 8) = h;
}

// -------- upsample: y1T[b][64*64][256] -> y1up[b][128*128][256] (UNPADDED), *s2 folded --------
__global__ __launch_bounds__(256)
void upsample_kernel(const ushort_t* __restrict__ y1T, const float* __restrict__ s2,
                     ushort_t* __restrict__ y1up) {
    int flat = blockIdx.x * 256 + threadIdx.x;
    int b = blockIdx.y;
    int ic8 = flat & 31;
    int pxl = flat >> 5;
    int ux = pxl & 127, uy = pxl >> 7;
    int jyA; float wyA;
    if (uy & 1) { jyA = uy >> 1;       wyA = 0.75f; }
    else        { jyA = (uy >> 1) - 1; wyA = 0.25f; }
    int jxA; float wxA;
    if (ux & 1) { jxA = ux >> 1;       wxA = 0.75f; }
    else        { jxA = (ux >> 1) - 1; wxA = 0.25f; }
    int yA = clampi(jyA, 0, 63), yB = clampi(jyA + 1, 0, 63);
    int xA = clampi(jxA, 0, 63), xB = clampi(jxA + 1, 0, 63);
    float wyB = 1.f - wyA, wxB = 1.f - wxA;
    const ushort_t* yb = y1T + (((size_t)b) << 20) + ic8 * 8;
    us8 qAA = *(const us8*)(yb + (size_t)(yA * 64 + xA) * 256);
    us8 qAB = *(const us8*)(yb + (size_t)(yA * 64 + xB) * 256);
    us8 qBA = *(const us8*)(yb + (size_t)(yB * 64 + xA) * 256);
    us8 qBB = *(const us8*)(yb + (size_t)(yB * 64 + xB) * 256);
    float4 slo = *(const float4*)(s2 + b * 256 + ic8 * 8);
    float4 shi = *(const float4*)(s2 + b * 256 + ic8 * 8 + 4);
    float sv[8] = {slo.x, slo.y, slo.z, slo.w, shi.x, shi.y, shi.z, shi.w};
    us8 h;
    #pragma unroll
    for (int j = 0; j < 8; j++) {
        float v = wyA * (wxA * bf2f(qAA[j]) + wxB * bf2f(qAB[j]))
                + wyB * (wxA * bf2f(qBA[j]) + wxB * bf2f(qBB[j]));
        h[j] = f2bf(v * sv[j]);
    }
    *(us8*)(y1up + ((size_t)b << 22) + (size_t)(uy * 128 + ux) * 256 + ic8 * 8) = h;
}

// =========== conv_mfma_ls: R1's proven 2-barrier LDS-staged kernel (93 us conv2-class) ===========
template<int IW, int OCTOT, int TPR, bool IS_CONV2>
__global__ __launch_bounds__(256, 2)
void conv_mfma_ls(const ushort_t* __restrict__ inp, const ushort_t* __restrict__ wT,
                  const float* __restrict__ dmod, const float* __restrict__ nza,
                  ushort_t* __restrict__ outT,
                  const float* __restrict__ rgb_in, const float* __restrict__ rw,
                  const float* __restrict__ rb, float* __restrict__ xout,
                  float* __restrict__ rgbo) {
    __shared__ __align__(16) ushort_t smem[28928];   // 57856 B total
    ushort_t* actS = smem;            // 10432 ushorts
    ushort_t* wS   = smem + 10432;    // 18496 ushorts

    const int b = blockIdx.z, ocg = blockIdx.y, tile = blockIdx.x;
    const int tyT = tile / TPR, txT = tile % TPR;
    const int ty0 = tyT * 16, tx0 = txT * 16;
    const int tid = threadIdx.x, lane = tid & 63, wave = tid >> 6;
    const int col = lane & 15, quad = lane >> 4;

    const ushort_t* inb = inp + (size_t)b * IW * IW * 256;

    int actOff[6]; bool actOk[6];
    #pragma unroll
    for (int i = 0; i < 6; i++) {
        int u = tid + 256 * i;
        int px_l = u >> 2, q = u & 3;
        int py = px_l / 18, pxx = px_l - py * 18;
        int gy = ty0 + py - 1, gx = tx0 + pxx - 1;
        bool ok = (u < 1296) && (gy >= 0) && (gy < IW) && (gx >= 0) && (gx < IW);
        actOk[i] = ok;
        actOff[i] = ok ? ((gy * IW + gx) * 256 + q * 8) : 0;
    }
    int wOff[9];
    #pragma unroll
    for (int i = 0; i < 9; i++) {
        int u = tid + 256 * i;
        int tap = u >> 8, oc = (u >> 2) & 63, q = u & 3;
        wOff[i] = (tap * OCTOT + ocg * 64 + oc) * 32 + q * 8;
    }
    const int KSTRIDE = 9 * OCTOT * 32;

    us8 aReg[6], wReg[9];
    const us8 zer = (us8)0;
#define LOADK(KC) { \
    _Pragma("unroll") for (int i = 0; i < 6; i++) \
        aReg[i] = actOk[i] ? *(const us8*)(inb + actOff[i] + (KC) * 32) : zer; \
    _Pragma("unroll") for (int i = 0; i < 9; i++) \
        wReg[i] = *(const us8*)(wT + wOff[i] + (KC) * KSTRIDE); }
#define STOREK() { \
    _Pragma("unroll") for (int i = 0; i < 6; i++) { \
        int u = tid + 256 * i; \
        if (u < 1296) *(us8*)(actS + (u & 3) * 2608 + (u >> 2) * 8) = aReg[i]; } \
    _Pragma("unroll") for (int i = 0; i < 9; i++) { \
        int u = tid + 256 * i; \
        *(us8*)(wS + (u & 3) * 4624 + (u >> 2) * 8) = wReg[i]; } }

    f32x4 acc[4][4];
    #pragma unroll
    for (int mt = 0; mt < 4; mt++)
        #pragma unroll
        for (int nt = 0; nt < 4; nt++) acc[mt][nt] = (f32x4)(0.f);

    LOADK(0);
    STOREK();
    __syncthreads();

    const ushort_t* bbase = actS + quad * 2608 + (72 * wave + col) * 8;
    const ushort_t* abase = wS + quad * 4624 + col * 8;

    for (int kc = 0; kc < 8; kc++) {
        if (kc < 7) LOADK(kc + 1);
        #pragma unroll
        for (int dx = 0; dx < 3; dx++) {
            bf16x8 bb[6];
            #pragma unroll
            for (int r = 0; r < 6; r++)
                bb[r] = *(const bf16x8*)(bbase + (r * 18 + dx) * 8);
            #pragma unroll
            for (int dy = 0; dy < 3; dy++) {
                const int tap = dy * 3 + dx;
                bf16x8 a[4];
                #pragma unroll
                for (int mt = 0; mt < 4; mt++)
                    a[mt] = *(const bf16x8*)(abase + (tap * 64 + mt * 16) * 8);
                #pragma unroll
                for (int mt = 0; mt < 4; mt++)
                    #pragma unroll
                    for (int nt = 0; nt < 4; nt++)
                        acc[mt][nt] = __builtin_amdgcn_mfma_f32_16x16x32_bf16(
                            a[mt], bb[nt + dy], acc[mt][nt], 0, 0, 0);
            }
        }
        __syncthreads();
        if (kc < 7) { STOREK(); }
        __syncthreads();
    }
#undef LOADK
#undef STOREK

    if constexpr (!IS_CONV2) {
        ushort_t* oS = smem;
        #pragma unroll
        for (int mt = 0; mt < 4; mt++) {
            int oc0 = ocg * 64 + mt * 16 + quad * 4;
            float4 dv = *(const float4*)(dmod + b * OCTOT + oc0);
            float4 nv = *(const float4*)(nza + b * OCTOT + oc0);
            float dva[4] = {dv.x, dv.y, dv.z, dv.w};
            float nva[4] = {nv.x, nv.y, nv.z, nv.w};
            #pragma unroll
            for (int nt = 0; nt < 4; nt++) {
                int px = (4 * wave + nt) * 16 + col;
                us4 h;
                #pragma unroll
                for (int r = 0; r < 4; r++) {
                    float t = acc[mt][nt][r] * dva[r] + nva[r];
                    t = (t >= 0.f) ? t : 0.1f * t;
                    h[r] = f2bf(t);
                }
                *(us4*)(oS + px * 80 + mt * 16 + quad * 4) = h;
            }
        }
        __syncthreads();
        #pragma unroll
        for (int p = 0; p < 8; p++) {
            int idx = tid + 256 * p;
            int px = idx >> 3, oc8 = idx & 7;
            us8 v = *(const us8*)(oS + px * 80 + oc8 * 8);
            int gy = ty0 + (px >> 4), gx = tx0 + (px & 15);
            *(us8*)(outT + ((size_t)b * IW * IW + gy * IW + gx) * 256 + ocg * 64 + oc8 * 8) = v;
        }
    } else {
        float dva[4][4], nva[4][4], rwa[3][4][4];
        #pragma unroll
        for (int mt = 0; mt < 4; mt++) {
            int oc0 = ocg * 64 + mt * 16 + quad * 4;
            float4 dv = *(const float4*)(dmod + b * 128 + oc0);
            float4 nv = *(const float4*)(nza + b * 128 + oc0);
            dva[mt][0] = dv.x; dva[mt][1] = dv.y; dva[mt][2] = dv.z; dva[mt][3] = dv.w;
            nva[mt][0] = nv.x; nva[mt][1] = nv.y; nva[mt][2] = nv.z; nva[mt][3] = nv.w;
            #pragma unroll
            for (int c = 0; c < 3; c++) {
                float4 rv = *(const float4*)(rw + c * 128 + oc0);
                rwa[c][mt][0] = rv.x; rwa[c][mt][1] = rv.y; rwa[c][mt][2] = rv.z; rwa[c][mt][3] = rv.w;
            }
        }
        #pragma unroll
        for (int nt = 0; nt < 4; nt++) {
            int uy = ty0 + 4 * wave + nt, ux = tx0 + col;
            float pc0 = 0.f, pc1 = 0.f, pc2 = 0.f;
            #pragma unroll
            for (int mt = 0; mt < 4; mt++) {
                int oc0 = ocg * 64 + mt * 16 + quad * 4;
                #pragma unroll
                for (int r = 0; r < 4; r++) {
                    float t = acc[mt][nt][r] * dva[mt][r] + nva[mt][r];
                    t = (t >= 0.f) ? t : 0.1f * t;
                    xout[(((size_t)b * 128 + oc0 + r) << 14) + (uy << 7) + ux] = t;
                    pc0 += rwa[0][mt][r] * t;
                    pc1 += rwa[1][mt][r] * t;
                    pc2 += rwa[2][mt][r] * t;
                }
            }
            pc0 += __shfl_xor(pc0, 16, 64); pc0 += __shfl_xor(pc0, 32, 64);
            pc1 += __shfl_xor(pc1, 16, 64); pc1 += __shfl_xor(pc1, 32, 64);
            pc2 += __shfl_xor(pc2, 16, 64); pc2 += __shfl_xor(pc2, 32, 64);
            if (quad == 0) {
                if (ocg == 0 && wave == 0) {
                    int jyA; float wyA;
                    if (uy & 1) { jyA = uy >> 1;       wyA = 0.75f; }
                    else        { jyA = (uy >> 1) - 1; wyA = 0.25f; }
                    int jxA; float wxA;
                    if (ux & 1) { jxA = ux >> 1;       wxA = 0.75f; }
                    else        { jxA = (ux >> 1) - 1; wxA = 0.25f; }
                    int yA = clampi(jyA, 0, 63), yB = clampi(jyA + 1, 0, 63);
                    int xA = clampi(jxA, 0, 63), xB = clampi(jxA + 1, 0, 63);
                    float wyB = 1.f - wyA, wxB = 1.f - wxA;
                    const float* rp3 = rgb_in + (((size_t)b * 3) << 12);
                    #pragma unroll
                    for (int c = 0; c < 3; c++) {
                        const float* rc = rp3 + ((size_t)c << 12);
                        float up = wyA * (wxA * rc[(yA << 6) + xA] + wxB * rc[(yA << 6) + xB])
                                 + wyB * (wxA * rc[(yB << 6) + xA] + wxB * rc[(yB << 6) + xB]);
                        if (c == 0) pc0 += rb[0] + up;
                        else if (c == 1) pc1 += rb[1] + up;
                        else pc2 += rb[2] + up;
                    }
                }
                const float S = 0.70710678118654752f;
                atomicAdd(rgbo + (((size_t)b * 3 + 0) << 14) + (uy << 7) + ux, pc0 * S);
                atomicAdd(rgbo + (((size_t)b * 3 + 1) << 14) + (uy << 7) + ux, pc1 * S);
                atomicAdd(rgbo + (((size_t)b * 3 + 2) << 14) + (uy << 7) + ux, pc2 * S);
            }
        }
    }
}

// =========== conv_mfma_rp: single barrier/kc, reg-staged COALESCED act, weights in regs ===========
// Wave = 16 oc x 256 px (R3 tiling, proven). Act double-buffered in LDS (2 x 20736 B).
// Act global reads: q = u&3 fastest -> 64 B contiguous per pixel (no L2 amplification).
// Act LDS write: plane-major [q][324 px-slots][8ic] -> identical content layout to R3's,
//   so the R3 compute loop is reused verbatim.
// Weights wf[9] in VGPRs, wfN[9] prefetched one kc ahead from flat wT[tap][oc][256ic].
// Single __syncthreads per kc: buf^1's readers all passed the previous barrier, so
//   ds_writes into buf^1 during kc are WAR-safe; the barrier's implicit waits publish them.
// Act loads are issued BEFORE weight loads each kc so STOREK's vmcnt wait leaves the
//   9 weight loads in flight.
template<int IW, int OCTOT, int TPR, bool IS_CONV2>
__global__ __launch_bounds__(256, 2)
void conv_mfma_rp(const ushort_t* __restrict__ inp, const ushort_t* __restrict__ wT,
                  const float* __restrict__ dmod, const float* __restrict__ nza,
                  ushort_t* __restrict__ outT,
                  const float* __restrict__ rgb_in, const float* __restrict__ rw,
                  const float* __restrict__ rb, float* __restrict__ xout,
                  float* __restrict__ rgbo) {
    __shared__ __align__(16) ushort_t actS[2 * 10368];   // 41472 B

    const int b = blockIdx.z, ocg = blockIdx.y, tile = blockIdx.x;
    const int tyT = tile / TPR, txT = tile % TPR;
    const int ty0 = tyT * 16, tx0 = txT * 16;
    const int tid = threadIdx.x, lane = tid & 63, wave = tid >> 6;
    const int col = lane & 15, quad = lane >> 4;

    const ushort_t* inb = inp + (size_t)b * IW * IW * 256;

    // staging descriptors (kc-invariant): global q-fastest (coalesced), LDS plane-major
    int actOff[6]; bool actOk[6]; int ldsOff[6];
    #pragma unroll
    for (int c = 0; c < 6; c++) {
        int u = tid + 256 * c;
        int px_l = u >> 2, q = u & 3;
        int py = px_l / 18, pxx = px_l - py * 18;
        int gy = ty0 + py - 1, gx = tx0 + pxx - 1;
        bool ok = (u < 1296) && (gy >= 0) && (gy < IW) && (gx >= 0) && (gx < IW);
        actOk[c] = ok;
        actOff[c] = ok ? ((gy * IW + gx) * 256 + q * 8) : 0;
        ldsOff[c] = (q * 324 + px_l) * 8;
    }
    // weight lane addressing: oc = ocg*64 + wave*16 + col, ic = kc*32 + quad*8
    const ushort_t* wlane = wT + (size_t)(ocg * 64 + wave * 16 + col) * 256 + quad * 8;
    const int TAPSTR = OCTOT * 256;

    us8 aReg[6];
    const us8 zer = (us8)0;
#define LOADK(KC) { \
    _Pragma("unroll") for (int c = 0; c < 6; c++) \
        aReg[c] = actOk[c] ? *(const us8*)(inb + actOff[c] + (KC) * 32) : zer; }
#define STOREK(BUF) { \
    _Pragma("unroll") for (int c = 0; c < 6; c++) { \
        int u = tid + 256 * c; \
        if (u < 1296) *(us8*)(actS + (BUF) * 10368 + ldsOff[c]) = aReg[c]; } }

    f32x4 acc[16];
    #pragma unroll
    for (int nt = 0; nt < 16; nt++) acc[nt] = (f32x4)(0.f);

    bf16x8 wf[9], wfN[9];
    LOADK(0);
    #pragma unroll
    for (int t = 0; t < 9; t++) wf[t] = *(const bf16x8*)(wlane + t * TAPSTR);
    STOREK(0);
    __syncthreads();   // buf0 + wf ready

    for (int kc = 0; kc < 8; kc++) {
        // prefetch NEXT kc: act globals first (oldest), then weights
        if (kc < 7) {
            LOADK(kc + 1);
            #pragma unroll
            for (int t = 0; t < 9; t++)
                wfN[t] = *(const bf16x8*)(wlane + t * TAPSTR + (kc + 1) * 32);
        }
        // compute from current buffer (weights already in regs, B-frags from LDS)
        const ushort_t* bbase = actS + (kc & 1) * 10368 + (quad * 324 + col) * 8;
        #pragma unroll
        for (int h = 0; h < 2; h++) {
            #pragma unroll
            for (int dx = 0; dx < 3; dx++) {
                bf16x8 bb[10];
                #pragma unroll
                for (int j = 0; j < 10; j++)
                    bb[j] = *(const bf16x8*)(bbase + ((h * 8 + j) * 18 + dx) * 8);
                #pragma unroll
                for (int dy = 0; dy < 3; dy++)
                    #pragma unroll
                    for (int nt = 0; nt < 8; nt++)
                        acc[h * 8 + nt] = __builtin_amdgcn_mfma_f32_16x16x32_bf16(
                            wf[dy * 3 + dx], bb[nt + dy], acc[h * 8 + nt], 0, 0, 0);
            }
        }
        // write next tile into the other buffer (WAR-safe: its readers passed last barrier)
        if (kc < 7) STOREK((kc & 1) ^ 1);
        __syncthreads();
        if (kc < 7) {
            #pragma unroll
            for (int t = 0; t < 9; t++) wf[t] = wfN[t];
        }
    }
#undef LOADK
#undef STOREK

    if constexpr (!IS_CONV2) {
        ushort_t* oS = actS;   // 256 px * 80 us = 40960 B <= 41472
        const int ocl = wave * 16 + quad * 4;
        const int oc0 = ocg * 64 + ocl;
        float4 dv = *(const float4*)(dmod + b * OCTOT + oc0);
        float4 nv = *(const float4*)(nza + b * OCTOT + oc0);
        float dva[4] = {dv.x, dv.y, dv.z, dv.w};
        float nva[4] = {nv.x, nv.y, nv.z, nv.w};
        #pragma unroll
        for (int nt = 0; nt < 16; nt++) {
            int px = nt * 16 + col;
            us4 h;
            #pragma unroll
            for (int r = 0; r < 4; r++) {
                float t = acc[nt][r] * dva[r] + nva[r];
                t = (t >= 0.f) ? t : 0.1f * t;
                h[r] = f2bf(t);
            }
            *(us4*)(oS + px * 80 + ocl) = h;
        }
        __syncthreads();
        #pragma unroll
        for (int p = 0; p < 8; p++) {
            int idx = tid + 256 * p;
            int px = idx >> 3, oc8 = idx & 7;
            us8 v = *(const us8*)(oS + px * 80 + oc8 * 8);
            int gy = ty0 + (px >> 4), gx = tx0 + (px & 15);
            *(us8*)(outT + ((size_t)b * IW * IW + gy * IW + gx) * 256 + ocg * 64 + oc8 * 8) = v;
        }
    } else {
        const int oc0 = ocg * 64 + wave * 16 + quad * 4;
        float4 dv = *(const float4*)(dmod + b * 128 + oc0);
        float4 nv = *(const float4*)(nza + b * 128 + oc0);
        float dva[4] = {dv.x, dv.y, dv.z, dv.w};
        float nva[4] = {nv.x, nv.y, nv.z, nv.w};
        float rwa[3][4];
        #pragma unroll
        for (int c = 0; c < 3; c++) {
            float4 rv = *(const float4*)(rw + c * 128 + oc0);
            rwa[c][0] = rv.x; rwa[c][1] = rv.y; rwa[c][2] = rv.z; rwa[c][3] = rv.w;
        }
        #pragma unroll
        for (int nt = 0; nt < 16; nt++) {
            int uy = ty0 + nt, ux = tx0 + col;
            float pc0 = 0.f, pc1 = 0.f, pc2 = 0.f;
            #pragma unroll
            for (int r = 0; r < 4; r++) {
                float t = acc[nt][r] * dva[r] + nva[r];
                t = (t >= 0.f) ? t : 0.1f * t;
                xout[(((size_t)b * 128 + oc0 + r) << 14) + (uy << 7) + ux] = t;
                pc0 += rwa[0][r] * t;
                pc1 += rwa[1][r] * t;
                pc2 += rwa[2][r] * t;
            }
            pc0 += __shfl_xor(pc0, 16, 64); pc0 += __shfl_xor(pc0, 32, 64);
            pc1 += __shfl_xor(pc1, 16, 64); pc1 += __shfl_xor(pc1, 32, 64);
            pc2 += __shfl_xor(pc2, 16, 64); pc2 += __shfl_xor(pc2, 32, 64);
            if (quad == 0) {
                if (ocg == 0 && wave == 0) {
                    int jyA; float wyA;
                    if (uy & 1) { jyA = uy >> 1;       wyA = 0.75f; }
                    else        { jyA = (uy >> 1) - 1; wyA = 0.25f; }
                    int jxA; float wxA;
                    if (ux & 1) { jxA = ux >> 1;       wxA = 0.75f; }
                    else        { jxA = (ux >> 1) - 1; wxA = 0.25f; }
                    int yA = clampi(jyA, 0, 63), yB = clampi(jyA + 1, 0, 63);
                    int xA = clampi(jxA, 0, 63), xB = clampi(jxA + 1, 0, 63);
                    float wyB = 1.f - wyA, wxB = 1.f - wxA;
                    const float* rp3 = rgb_in + (((size_t)b * 3) << 12);
                    #pragma unroll
                    for (int c = 0; c < 3; c++) {
                        const float* rc = rp3 + ((size_t)c << 12);
                        float up = wyA * (wxA * rc[(yA << 6) + xA] + wxB * rc[(yA << 6) + xB])
                                 + wyB * (wxA * rc[(yB << 6) + xA] + wxB * rc[(yB << 6) + xB]);
                        if (c == 0) pc0 += rb[0] + up;
                        else if (c == 1) pc1 += rb[1] + up;
                        else pc2 += rb[2] + up;
                    }
                }
                const float S = 0.70710678118654752f;
                atomicAdd(rgbo + (((size_t)b * 3 + 0) << 14) + (uy << 7) + ux, pc0 * S);
                atomicAdd(rgbo + (((size_t)b * 3 + 1) << 14) + (uy << 7) + ux, pc1 * S);
                atomicAdd(rgbo + (((size_t)b * 3 + 2) << 14) + (uy << 7) + ux, pc2 * S);
            }
        }
    }
}

extern "C" void kernel_launch(void* const* d_in, const int* in_sizes, int n_in,
                              void* d_out, int out_size, void* d_ws, size_t ws_size,
                              hipStream_t stream) {
    (void)in_sizes; (void)n_in; (void)out_size; (void)ws_size;
    const float* x     = (const float*)d_in[0];
    const float* w     = (const float*)d_in[1];
    const float* n     = (const float*)d_in[2];
    const float* rgb   = (const float*)d_in[3];
    const float* cw1   = (const float*)d_in[4];
    const float* A1w   = (const float*)d_in[5];
    const float* A1b   = (const float*)d_in[6];
    const float* B1w   = (const float*)d_in[7];
    const float* B1b   = (const float*)d_in[8];
    const float* cw2   = (const float*)d_in[9];
    const float* A2w   = (const float*)d_in[10];
    const float* A2b   = (const float*)d_in[11];
    const float* B2w   = (const float*)d_in[12];
    const float* B2b   = (const float*)d_in[13];
    const float* rgbw  = (const float*)d_in[14];
    const float* rgbb  = (const float*)d_in[15];

    char* ws = (char*)d_ws;
    float* s1 = (float*)(ws);
    float* s2 = (float*)(ws + 8192);
    float* d1 = (float*)(ws + 16384);
    float* d2 = (float*)(ws + 24576);
    float* n1 = (float*)(ws + 28672);
    float* n2 = (float*)(ws + 36864);
    ushort_t* wT1  = (ushort_t*)(ws + 40960);          // 1179648 B  [kc][tap][256oc][32ic]
    ushort_t* wT2  = (ushort_t*)(ws + 1220608);        // 589824 B   [tap][128oc][256ic]
    ushort_t* xTp  = (ushort_t*)(ws + 1810432);        // 16777216 B [b][64*64][256]
    ushort_t* y1up = (ushort_t*)(ws + 18587648);       // 67108864 B [b][128*128][256]
    ushort_t* y1T  = (ushort_t*)(ws + 85696512);       // 16777216 B [b][64*64][256]

    float* xout = (float*)d_out;
    float* rgbo = xout + (size_t)BN * C2 * 128 * 128;

    hipMemsetAsync(rgbo, 0, (size_t)BN * 3 * 128 * 128 * 4, stream);

    affine_kernel<<<1792, 256, 0, stream>>>(w, n, A1w, A1b, B1w, B1b, A2w, A2b, B2w, B2b,
                                            s1, s2, n1, n2);
    demod_kernel<<<768, 256, 0, stream>>>(cw1, cw2, s1, s2, d1, d2);
    wprep_kernel<<<(589824 + 294912) / 256, 256, 0, stream>>>(cw1, cw2, wT1, wT2);
    xprep_kernel<<<dim3(256, BN), 512, 0, stream>>>(x, s1, xTp);
    conv_mfma_ls<64, 256, 4, false><<<dim3(16, 4, BN), 256, 0, stream>>>(
        xTp, wT1, d1, n1, y1T, nullptr, nullptr, nullptr, nullptr, nullptr);
    upsample_kernel<<<dim3(2048, BN), 256, 0, stream>>>(y1T, s2, y1up);
    conv_mfma_rp<128, 128, 8, true><<<dim3(64, 2, BN), 256, 0, stream>>>(
        y1up, wT2, d2, n2, nullptr, rgb, rgbw, rgbb, xout, rgbo);
}